// Round 1
// baseline (2842.361 us; speedup 1.0000x reference)
//
#include <hip/hip_runtime.h>

#define BB 8
#define TT 300
#define AA 3
#define VV 25
#define PP 2
#define CC 64
#define FF 64
#define NN 4
#define KK 9
#define T_VALID (TT - KK + 1)   // 292

#define TPW 8      // t-values per wave
#define TBLK 32    // t-values per block (4 waves)

// x:  (B, T, A, V*P, C)  float32
// ker:(N, K, F, C)       float32
// nb: (V, N)             int32
// out:(B, T, A, V*P, F)  float32  (t >= 292 zeroed)
__global__ __launch_bounds__(256) void glc_kernel(const float* __restrict__ x,
                                                  const float* __restrict__ ker,
                                                  const int* __restrict__ nb,
                                                  float* __restrict__ out) {
    const int xTs = AA * VV * PP * CC;   // 9600 floats per t-step
    const int oTs = AA * VV * PP * FF;   // 9600

    // blockIdx.x encodes (b, a, u, p); blockIdx.y is the t-tile
    int rb = blockIdx.x;
    int p = rb % PP;  rb /= PP;
    int u = rb % VV;  rb /= VV;
    int a = rb % AA;
    int b = rb / AA;

    const int lane = threadIdx.x & 63;
    const int wave = __builtin_amdgcn_readfirstlane((int)(threadIdx.x >> 6));
    const int f    = lane;
    const int t0   = blockIdx.y * TBLK + wave * TPW;

    float acc[TPW];
#pragma unroll
    for (int i = 0; i < TPW; ++i) acc[i] = 0.f;

    if (t0 < T_VALID) {
        // neighbor gather indices (uniform across wave)
        int vn[NN];
#pragma unroll
        for (int n = 0; n < NN; ++n) vn[n] = nb[u * NN + n];

        // clamped per-t row offsets (boundary waves read row 291; result discarded)
        int toff[TPW];
#pragma unroll
        for (int tt = 0; tt < TPW; ++tt) {
            int t = t0 + tt;
            if (t > T_VALID - 1) t = T_VALID - 1;
            toff[tt] = t * xTs;
        }

        const float* xb = x + b * (TT * xTs) + a * (VV * PP * CC) + p * CC;

#pragma unroll
        for (int n = 0; n < NN; ++n) {
            const float* xn = xb + vn[n] * (PP * CC);
            const float* kn = ker + (n * KK) * (FF * CC) + f * CC;
            for (int k = 0; k < KK; ++k) {
                const float* kw = kn + k * (FF * CC);
                const int kx = k * xTs;
#pragma unroll 4
                for (int c4 = 0; c4 < CC; c4 += 4) {
                    const float4 w4 = *reinterpret_cast<const float4*>(kw + c4);
#pragma unroll
                    for (int tt = 0; tt < TPW; ++tt) {
                        const float4 x4 = *reinterpret_cast<const float4*>(xn + toff[tt] + kx + c4);
                        acc[tt] = fmaf(w4.x, x4.x, acc[tt]);
                        acc[tt] = fmaf(w4.y, x4.y, acc[tt]);
                        acc[tt] = fmaf(w4.z, x4.z, acc[tt]);
                        acc[tt] = fmaf(w4.w, x4.w, acc[tt]);
                    }
                }
            }
        }
    }

    // write (kernel itself produces the K-1 zero-pad tail)
    float* ob = out + b * (TT * oTs) + a * (VV * PP * FF) + (u * PP + p) * FF + f;
#pragma unroll
    for (int tt = 0; tt < TPW; ++tt) {
        int t = t0 + tt;
        if (t < TT) {
            ob[t * oTs] = (t < T_VALID) ? acc[tt] : 0.f;
        }
    }
}

extern "C" void kernel_launch(void* const* d_in, const int* in_sizes, int n_in,
                              void* d_out, int out_size, void* d_ws, size_t ws_size,
                              hipStream_t stream) {
    const float* x   = (const float*)d_in[0];
    const float* ker = (const float*)d_in[1];
    const int*   nb  = (const int*)d_in[2];
    float* out = (float*)d_out;

    dim3 grid(BB * AA * VV * PP, (TT + TBLK - 1) / TBLK);  // 1200 x 10
    glc_kernel<<<grid, 256, 0, stream>>>(x, ker, nb, out);
}

// Round 2
// 194.536 us; speedup vs baseline: 14.6110x; 14.6110x over previous
//
#include <hip/hip_runtime.h>

typedef __attribute__((ext_vector_type(8))) short short8;
typedef __attribute__((ext_vector_type(4))) float f32x4;

#define XS_BYTES 73728   // 8 slots * 144 rows * 64 B (32 bf16 c-half)
#define WS_BYTES 8192    // 2 x 4KB weight frag buffers

__device__ __forceinline__ unsigned short f2bf(float f) {
  union { float f; unsigned u; } c; c.f = f;
  unsigned u = c.u;
  return (unsigned short)((u + 0x7fffu + ((u >> 16) & 1u)) >> 16);  // RNE
}

__device__ __forceinline__ unsigned swz(unsigned off) {
  // spread 64B-row-strided 16B accesses across banks; bijective within 128B pairs
  return off ^ (((off >> 6) & 7u) << 4);
}

extern "C" __global__ __launch_bounds__(256, 2)
void glc_mfma(const float* __restrict__ x, const float* __restrict__ ker,
              const int* __restrict__ nb, float* __restrict__ out) {
  __shared__ __align__(16) char lds[XS_BYTES + WS_BYTES];
  char* xs  = lds;
  char* wsb = lds + XS_BYTES;

  const int bid = blockIdx.x;
  const int tt = bid % 5;
  const int up = (bid / 5) % 13;
  const int a  = (bid / 65) % 3;
  const int b  = bid / 195;
  const int t0 = tt * 64;
  const int u0 = up * 2;
  const bool updup = (up == 12);   // u-pair (24,24): waves 2,3 duplicate

  const int tid  = threadIdx.x;
  const int lane = tid & 63;
  const int wave = tid >> 6;
  const int uloc = wave >> 1;

  // x-staging roles: slot = (uloc*4+n), 32 threads per slot
  const int sslot = tid >> 5;
  const int scu   = tid & 3;            // c-octet (8 fp32 -> 8 bf16)
  const int srr   = (tid >> 2) & 7;
  const int su    = u0 + ((updup ? 0 : 1) & (sslot >> 2));
  const int sv    = nb[su * 4 + (sslot & 3)];

  // W-staging roles
  const int wf = tid >> 2;              // f row 0..63 (scu = c-octet)

  f32x4 acc[4][4];
#pragma unroll
  for (int i = 0; i < 4; ++i)
#pragma unroll
    for (int j = 0; j < 4; ++j) acc[i][j] = (f32x4){0.f, 0.f, 0.f, 0.f};

  for (int ch = 0; ch < 2; ++ch) {
    // ---- stage x (c-half) : 8 slots x 144 rows x 32c bf16, swizzled ----
#pragma unroll 4
    for (int it = 0; it < 18; ++it) {
      int r = it * 8 + srr;
      int t = t0 + (r >> 1); if (t > 299) t = 299;   // clamp; garbage discarded
      int p = r & 1;
      const float* src = x + ((size_t)((b * 300 + t) * 3 + a) * 50 + (sv * 2 + p)) * 64
                           + ch * 32 + scu * 8;
      f32x4 a0 = *(const f32x4*)src;
      f32x4 a1 = *(const f32x4*)(src + 4);
      short8 h = {(short)f2bf(a0.x), (short)f2bf(a0.y), (short)f2bf(a0.z), (short)f2bf(a0.w),
                  (short)f2bf(a1.x), (short)f2bf(a1.y), (short)f2bf(a1.z), (short)f2bf(a1.w)};
      unsigned off = (unsigned)(sslot * 9216 + r * 64 + scu * 16);
      *(short8*)(xs + swz(off)) = h;
    }
    // ---- stage W(nk=0) prologue into buf0 (fragment-linear layout) ----
    {
      const float* wsrc = ker + (size_t)wf * 64 + ch * 32 + scu * 8;
      f32x4 w0 = *(const f32x4*)wsrc;
      f32x4 w1 = *(const f32x4*)(wsrc + 4);
      short8 h = {(short)f2bf(w0.x), (short)f2bf(w0.y), (short)f2bf(w0.z), (short)f2bf(w0.w),
                  (short)f2bf(w1.x), (short)f2bf(w1.y), (short)f2bf(w1.z), (short)f2bf(w1.w)};
      unsigned off = (unsigned)((((wf >> 4) * 64) + (scu << 4) + (wf & 15)) * 16);
      *(short8*)(wsb + off) = h;
    }
    __syncthreads();

    int nk = 0;
    for (int n = 0; n < 4; ++n) {
      const unsigned sbase = (unsigned)((uloc * 4 + n) * 9216);
      for (int k = 0; k < 9; ++k, ++nk) {
        // prefetch next (n,k) weights global->regs (overlaps with MFMAs below)
        f32x4 w0, w1;
        const bool hn = (nk < 35);
        if (hn) {
          const float* wsrc = ker + (size_t)((nk + 1) * 64 + wf) * 64 + ch * 32 + scu * 8;
          w0 = *(const f32x4*)wsrc;
          w1 = *(const f32x4*)(wsrc + 4);
        }
        // A fragments (fragment-linear: conflict-free stride-1 b128)
        const char* wb = wsb + (nk & 1) * 4096;
        short8 af[4];
#pragma unroll
        for (int ft = 0; ft < 4; ++ft)
          af[ft] = *(const short8*)(wb + ft * 1024 + lane * 16);
        // B fragments + MFMAs: wave owns 4 col-tiles (64 cols)
#pragma unroll
        for (int i = 0; i < 4; ++i) {
          const int ctl = (wave * 4 + i) & 7;
          unsigned off = sbase
                       + (unsigned)((ctl * 16 + 2 * k + (lane & 15)) * 64 + (lane >> 4) * 16);
          short8 bv = *(const short8*)(xs + swz(off));
#pragma unroll
          for (int ft = 0; ft < 4; ++ft)
            acc[ft][i] = __builtin_amdgcn_mfma_f32_16x16x32_bf16(af[ft], bv, acc[ft][i], 0, 0, 0);
        }
        // write prefetched weights to other buffer
        if (hn) {
          short8 h = {(short)f2bf(w0.x), (short)f2bf(w0.y), (short)f2bf(w0.z), (short)f2bf(w0.w),
                      (short)f2bf(w1.x), (short)f2bf(w1.y), (short)f2bf(w1.z), (short)f2bf(w1.w)};
          unsigned off = (unsigned)((((wf >> 4) * 64) + (scu << 4) + (wf & 15)) * 16);
          *(short8*)(wsb + ((nk + 1) & 1) * 4096 + off) = h;
        }
        __syncthreads();
      }
    }
  }

  // ---- epilogue: D tile (ft,i): col = lane&15, f = ft*16 + (lane>>4)*4 + reg ----
  if (updup && uloc) return;            // skip duplicate u=24 stores
  const int u = u0 + uloc;
  const int fbase = (lane >> 4) * 4;
  const f32x4 z4 = (f32x4){0.f, 0.f, 0.f, 0.f};
#pragma unroll
  for (int i = 0; i < 4; ++i) {
    const int colg = wave * 64 + i * 16 + (lane & 15);
    const int cc = colg & 127;          // within-u column: t-rel (p-minor)
    const int t = t0 + (cc >> 1);
    const int p = cc & 1;
    if (t < 300) {
      float* dst = out + ((size_t)((b * 300 + t) * 3 + a) * 50 + (u * 2 + p)) * 64 + fbase;
      const bool valid = (t < 292);     // t>=292: zero-pad tail
#pragma unroll
      for (int ft = 0; ft < 4; ++ft) {
        f32x4 v = valid ? acc[ft][i] : z4;
        *(f32x4*)(dst + ft * 16) = v;
      }
    }
  }
}

extern "C" void kernel_launch(void* const* d_in, const int* in_sizes, int n_in,
                              void* d_out, int out_size, void* d_ws, size_t ws_size,
                              hipStream_t stream) {
  const float* x   = (const float*)d_in[0];
  const float* ker = (const float*)d_in[1];
  const int*   nb  = (const int*)d_in[2];
  float* out = (float*)d_out;

  // grid: 8 b * 3 a * 13 u-pairs * 5 t-tiles
  glc_mfma<<<dim3(8 * 3 * 13 * 5), dim3(256), 0, stream>>>(x, ker, nb, out);
}

// Round 3
// 147.236 us; speedup vs baseline: 19.3048x; 1.3213x over previous
//
#include <hip/hip_runtime.h>
#include <hip/hip_bf16.h>

typedef __attribute__((ext_vector_type(8))) short short8;
typedef __attribute__((ext_vector_type(4))) float f32x4;
typedef __attribute__((ext_vector_type(4))) unsigned int u32x4;

#define XS_BYTES 73728   // 8 slots * 144 rows * 64 B (32-bf16 c-half), swizzled

__device__ __forceinline__ unsigned swz(unsigned off) {
  return off ^ (((off >> 6) & 7u) << 4);
}

__device__ __forceinline__ unsigned pk2(float lo, float hi) {
  union { __hip_bfloat162 h; unsigned u; } c;
  c.h = __float22bfloat162_rn(float2{lo, hi});
  return c.u;
}

// one-time: ker (fp32, N*K x F x C) -> bf16 fragment-linear in ws
// frag(ch,nk,ft,lane) holds W[f=ft*16+(lane&15), c=ch*32+(lane>>4)*8 .. +8]
extern "C" __global__ void w_prep(const float* __restrict__ ker, u32x4* __restrict__ wsw) {
  const int nk = blockIdx.x % 36;
  const int ch = blockIdx.x / 36;
  const int lane = threadIdx.x & 63;
  const int ft = threadIdx.x >> 6;
  const float* src = ker + (size_t)(nk * 64 + ft * 16 + (lane & 15)) * 64
                         + ch * 32 + (lane >> 4) * 8;
  f32x4 a0 = *(const f32x4*)src;
  f32x4 a1 = *(const f32x4*)(src + 4);
  u32x4 h = { pk2(a0.x, a0.y), pk2(a0.z, a0.w), pk2(a1.x, a1.y), pk2(a1.z, a1.w) };
  wsw[((ch * 36 + nk) * 4 + ft) * 64 + lane] = h;
}

extern "C" __global__ __launch_bounds__(256, 2)
void glc_mfma(const float* __restrict__ x, const short8* __restrict__ wsw,
              const int* __restrict__ nb, float* __restrict__ out) {
  __shared__ __align__(16) char xs[XS_BYTES];

  const int bid = blockIdx.x;
  const int tt = bid % 5;
  const int up = (bid / 5) % 13;
  const int a  = (bid / 65) % 3;
  const int b  = bid / 195;
  const int t0 = tt * 64;
  const int u0 = up * 2;
  const bool updup = (up == 12);   // u-pair (24,24): waves 2,3 duplicate

  const int tid  = threadIdx.x;
  const int lane = tid & 63;
  const int wave = tid >> 6;
  const int uloc = wave >> 1;

  // x-staging roles: slot = (uloc*4+n), 32 threads per slot
  const int sslot = tid >> 5;
  const int scu   = tid & 3;            // c-octet
  const int srr   = (tid >> 2) & 7;
  const int su    = u0 + ((updup ? 0 : 1) & (sslot >> 2));
  const int sv    = nb[su * 4 + (sslot & 3)];

  f32x4 acc[4][4];
#pragma unroll
  for (int i = 0; i < 4; ++i)
#pragma unroll
    for (int j = 0; j < 4; ++j) acc[i][j] = (f32x4){0.f, 0.f, 0.f, 0.f};

  // B-fragment column offsets (per wave col-tile i)
  unsigned coff[4];
#pragma unroll
  for (int i = 0; i < 4; ++i) {
    const int ctl = (wave * 4 + i) & 7;
    coff[i] = (unsigned)((ctl * 16 + (lane & 15)) * 64 + (lane >> 4) * 16);
  }

  // staging source base (t and p terms added per row)
  const float* xb = x + (size_t)b * (300 * 9600) + (size_t)a * 3200 + (sv * 2) * 64 + scu * 8;

  for (int ch = 0; ch < 2; ++ch) {
    if (ch) __syncthreads();            // protect prev-half reads
#pragma unroll 3
    for (int it = 0; it < 18; ++it) {
      int r = it * 8 + srr;
      int t = t0 + (r >> 1); if (t > 299) t = 299;   // clamp; garbage discarded
      const float* src = xb + (size_t)t * 9600 + (r & 1) * 64 + ch * 32;
      f32x4 a0 = *(const f32x4*)src;
      f32x4 a1 = *(const f32x4*)(src + 4);
      u32x4 h = { pk2(a0.x, a0.y), pk2(a0.z, a0.w), pk2(a1.x, a1.y), pk2(a1.z, a1.w) };
      unsigned off = (unsigned)(sslot * 9216 + r * 64 + scu * 16);
      *(u32x4*)(xs + swz(off)) = h;
    }
    __syncthreads();

    const short8* wp = wsw + (size_t)ch * (36 * 4 * 64);
    short8 wcur[4];
#pragma unroll
    for (int ft = 0; ft < 4; ++ft) wcur[ft] = wp[ft * 64 + lane];

    int nk = 0;
#pragma unroll 1
    for (int n = 0; n < 4; ++n) {
      const unsigned sbase = (unsigned)((uloc * 4 + n) * 9216);
      for (int k = 0; k < 9; ++k, ++nk) {
        short8 wnxt[4];
        const bool hn = (nk < 35);
        if (hn) {
#pragma unroll
          for (int ft = 0; ft < 4; ++ft)
            wnxt[ft] = wp[(nk + 1) * 256 + ft * 64 + lane];
        }
        const unsigned krow = sbase + (unsigned)(k * 128);
#pragma unroll
        for (int i = 0; i < 4; ++i) {
          short8 bv = *(const short8*)(xs + swz(krow + coff[i]));
#pragma unroll
          for (int ft = 0; ft < 4; ++ft)
            acc[ft][i] = __builtin_amdgcn_mfma_f32_16x16x32_bf16(wcur[ft], bv, acc[ft][i], 0, 0, 0);
        }
        if (hn) {
#pragma unroll
          for (int ft = 0; ft < 4; ++ft) wcur[ft] = wnxt[ft];
        }
      }
    }
  }

  // ---- epilogue: D tile (ft,i): col = lane&15, f = ft*16 + (lane>>4)*4 + reg ----
  if (updup && uloc) return;            // skip duplicate u=24 stores
  const int u = u0 + uloc;
  const int fbase = (lane >> 4) * 4;
  const f32x4 z4 = (f32x4){0.f, 0.f, 0.f, 0.f};
#pragma unroll
  for (int i = 0; i < 4; ++i) {
    const int colg = wave * 64 + i * 16 + (lane & 15);
    const int cc = colg & 127;          // within-u column: t-rel (p-minor)
    const int t = t0 + (cc >> 1);
    const int p = cc & 1;
    if (t < 300) {
      float* dst = out + ((size_t)((b * 300 + t) * 3 + a) * 50 + (u * 2 + p)) * 64 + fbase;
      const bool valid = (t < 292);     // t>=292: zero-pad tail
#pragma unroll
      for (int ft = 0; ft < 4; ++ft) {
        f32x4 v = valid ? acc[ft][i] : z4;
        *(f32x4*)(dst + ft * 16) = v;
      }
    }
  }
}

extern "C" void kernel_launch(void* const* d_in, const int* in_sizes, int n_in,
                              void* d_out, int out_size, void* d_ws, size_t ws_size,
                              hipStream_t stream) {
  const float* x   = (const float*)d_in[0];
  const float* ker = (const float*)d_in[1];
  const int*   nb  = (const int*)d_in[2];
  float* out = (float*)d_out;

  w_prep<<<dim3(72), dim3(256), 0, stream>>>(ker, (u32x4*)d_ws);
  glc_mfma<<<dim3(8 * 3 * 13 * 5), dim3(256), 0, stream>>>(x, (const short8*)d_ws, nb, out);
}